// Round 12
// baseline (1137.408 us; speedup 1.0000x reference)
//
#include <hip/hip_runtime.h>

#define NN 50000
#define NE 1600000
#define NR 8
#define ND 128
#define NL 3
#define RN (NR * NN)
#define SCAN_BLK 1024
#define NB ((RN + SCAN_BLK - 1) / SCAN_BLK)  // 391
#define LN_EPS 1e-5f
#define PADB 136   // bf16 elems per wave-tile row (272 B row stride)
#define PADB2 68   // dwords per wave-tile row
#define PADF 132   // f32 elems per epilogue scratch row (8448 B per wave region)

// fused prep kernel region sizes
#define PREP_G (NN * 64)        // gather dwords
#define PREP_W (27 * 16384)     // wprep elems
#define PREP_TOT (RN + PREP_G + PREP_W)

typedef __attribute__((ext_vector_type(8))) short short8;
typedef __attribute__((ext_vector_type(4))) float float4v;

__device__ __forceinline__ float bflo(unsigned u) { return __uint_as_float(u << 16); }
__device__ __forceinline__ float bfhi(unsigned u) { return __uint_as_float(u & 0xFFFF0000u); }
__device__ __forceinline__ unsigned f2bf(float f) {
    unsigned u = __float_as_uint(f);
    return (u + 0x7FFFu + ((u >> 16) & 1u)) >> 16;   // RNE
}
__device__ __forceinline__ unsigned pack2(float lo, float hi) {
    return f2bf(lo) | (f2bf(hi) << 16);
}

// fused: cnt zero | h gather (row-major bf16x2) | weight prep (B-frag layout)
__global__ __launch_bounds__(256) void k_prep0(const int* __restrict__ x,
                                               const float* __restrict__ emb,
                                               const float* __restrict__ w_rel,
                                               const float* __restrict__ w_root,
                                               int* __restrict__ cnt,
                                               unsigned* __restrict__ h,
                                               unsigned short* __restrict__ wb) {
    int i = blockIdx.x * 256 + threadIdx.x;
    if (i < RN) {
        cnt[i] = 0;
        return;
    }
    i -= RN;
    if (i < PREP_G) {
        int n = i >> 6, dw = i & 63;
        float2 v = *(const float2*)&emb[(size_t)x[n] * ND + 2 * dw];
        h[i] = pack2(v.x, v.y);
        return;
    }
    i -= PREP_G;
    if (i >= PREP_W) return;
    int m = i >> 14;
    int idx = i & 16383;
    int j = idx & 7;
    int lane = (idx >> 3) & 63;
    int ft = (idx >> 9) & 7;
    int kk = idx >> 12;
    int row = kk * 32 + (lane >> 4) * 8 + j;
    int col = ft * 16 + (lane & 15);
    const float* W = (m < 24) ? (w_rel + (size_t)m * 16384)
                              : (w_root + (size_t)(m - 24) * 16384);
    wb[i] = (unsigned short)f2bf(W[row * ND + col]);
}

__global__ __launch_bounds__(256) void k_count(const int* __restrict__ dst,
                                               const int* __restrict__ et,
                                               int* __restrict__ cnt) {
    int i = blockIdx.x * 256 + threadIdx.x;
    if (i >= NE / 4) return;
    int4 d4 = ((const int4*)dst)[i];
    int4 t4 = ((const int4*)et)[i];
    atomicAdd(&cnt[t4.x * NN + d4.x], 1);
    atomicAdd(&cnt[t4.y * NN + d4.y], 1);
    atomicAdd(&cnt[t4.z * NN + d4.z], 1);
    atomicAdd(&cnt[t4.w * NN + d4.w], 1);
}

// scan over cnt -> rowstart (exclusive)
__global__ __launch_bounds__(256) void k_scan1(const int* __restrict__ cnt,
                                               int* __restrict__ rowstart,
                                               int* __restrict__ bsum) {
    __shared__ int tmp[256];
    int t = threadIdx.x;
    int base = blockIdx.x * SCAN_BLK + t * 4;
    int v[4];
#pragma unroll
    for (int i = 0; i < 4; i++) v[i] = (base + i < RN) ? cnt[base + i] : 0;
    int local = v[0] + v[1] + v[2] + v[3];
    tmp[t] = local;
    __syncthreads();
    for (int off = 1; off < 256; off <<= 1) {
        int x = (t >= off) ? tmp[t - off] : 0;
        __syncthreads();
        tmp[t] += x;
        __syncthreads();
    }
    int run = tmp[t] - local;
    if (t == 255) bsum[blockIdx.x] = tmp[t];
#pragma unroll
    for (int i = 0; i < 4; i++) {
        if (base + i < RN) rowstart[base + i] = run;
        run += v[i];
    }
}

__global__ __launch_bounds__(256) void k_scan2(const int* __restrict__ bsum,
                                               int* __restrict__ boff) {
    __shared__ int tmp[256];
    int t = threadIdx.x;
    int v0 = (2 * t < NB) ? bsum[2 * t] : 0;
    int v1 = (2 * t + 1 < NB) ? bsum[2 * t + 1] : 0;
    int local = v0 + v1;
    tmp[t] = local;
    __syncthreads();
    for (int off = 1; off < 256; off <<= 1) {
        int x = (t >= off) ? tmp[t - off] : 0;
        __syncthreads();
        tmp[t] += x;
        __syncthreads();
    }
    int excl = tmp[t] - local;
    if (2 * t < NB) boff[2 * t] = excl;
    if (2 * t + 1 < NB) boff[2 * t + 1] = excl + v0;
}

__global__ __launch_bounds__(256) void k_scan3(int* __restrict__ rowstart,
                                               const int* __restrict__ boff) {
    int i = blockIdx.x * 256 + threadIdx.x;
    if (i < RN) rowstart[i] += boff[i >> 10];
    if (i == 0) rowstart[RN] = NE;
}

__global__ __launch_bounds__(256) void k_fill(const int* __restrict__ src,
                                              const int* __restrict__ dst,
                                              const int* __restrict__ et,
                                              const int* __restrict__ rowstart,
                                              int* __restrict__ cnt,
                                              int* __restrict__ adj) {
    int i = blockIdx.x * 256 + threadIdx.x;
    if (i >= NE / 4) return;
    int4 s4 = ((const int4*)src)[i];
    int4 d4 = ((const int4*)dst)[i];
    int4 t4 = ((const int4*)et)[i];
    int seg, c;
    seg = t4.x * NN + d4.x; c = atomicSub(&cnt[seg], 1); adj[rowstart[seg] + c - 1] = s4.x;
    seg = t4.y * NN + d4.y; c = atomicSub(&cnt[seg], 1); adj[rowstart[seg] + c - 1] = s4.y;
    seg = t4.z * NN + d4.z; c = atomicSub(&cnt[seg], 1); adj[rowstart[seg] + c - 1] = s4.z;
    seg = t4.w * NN + d4.w; c = atomicSub(&cnt[seg], 1); adj[rowstart[seg] + c - 1] = s4.w;
}

// Fused RGCN layer, WAVE-AUTONOMOUS (R10 structure): block = 64 nodes, 4 waves;
// each wave owns a 16-row m-tile + private LDS region; zero __syncthreads.
// NEW vs R10: all 8 relations' (st,en) prefetched into registers up-front
// (2-deep chain instead of 3-deep), and mean scale computed from en-st
// (no inv[] load).
__global__ __launch_bounds__(256) void k_layer(const unsigned* __restrict__ h32,
                                               const int* __restrict__ adj,
                                               const int* __restrict__ rowstart,
                                               const unsigned short* __restrict__ wrel,
                                               const unsigned short* __restrict__ wroot,
                                               const float* __restrict__ bias,
                                               const float* __restrict__ gamma,
                                               const float* __restrict__ beta,
                                               float* __restrict__ out_f,
                                               unsigned* __restrict__ out_h,
                                               int add_res, int last) {
    __shared__ float SLF[4][16 * PADF];              // per-wave 8448 B regions

    int tid = threadIdx.x;
    int wave = tid >> 6, lane = tid & 63;
    int quad = lane >> 4, l15 = lane & 15;
    int n0 = blockIdx.x * 64;
    int w0 = n0 + wave * 16;                         // wave's first global row

    float* WF = SLF[wave];                           // fp32 [16][PADF] epilogue view
    unsigned short* WB16 = (unsigned short*)WF;      // bf16 [16][PADB] tile view
    unsigned* WB32 = (unsigned*)WF;                  // dword [16][PADB2] tile view

    // prefetch CSR bounds for this wave's two batch rows, all 8 relations
    int gA = w0 + quad;                              // batch 0 row (tile row = quad)
    int gB = w0 + 4 + quad;                          // batch 1 row (tile row = 4+quad)
    int cAi = gA < NN ? gA : NN - 1;
    int cBi = gB < NN ? gB : NN - 1;
    int st2[2][8], en2[2][8];
#pragma unroll
    for (int r = 0; r < NR; r++) {
        st2[0][r] = rowstart[r * NN + cAi];
        en2[0][r] = rowstart[r * NN + cAi + 1];
        st2[1][r] = rowstart[r * NN + cBi];
        en2[1][r] = rowstart[r * NN + cBi + 1];
    }

    float4v acc[8];
#pragma unroll
    for (int i = 0; i < 8; i++) acc[i] = (float4v){0.f, 0.f, 0.f, 0.f};

    for (int r = 0; r < NR; r++) {
        // gather+mean: 4 batches of 4 quad-chains (rows 0..15)
#pragma unroll
        for (int b = 0; b < 4; b++) {
            int row = b * 4 + quad;
            int g = w0 + row;
            float a0 = 0.f, a1 = 0.f, a2 = 0.f, a3 = 0.f,
                  a4 = 0.f, a5 = 0.f, a6 = 0.f, a7 = 0.f;
            if (g < NN) {
                int st, en;
                if (b < 2) { st = st2[b][r]; en = en2[b][r]; }
                else {
                    int seg = r * NN + g;
                    st = rowstart[seg]; en = rowstart[seg + 1];
                }
                st = st < 0 ? 0 : st;
                en = en > NE ? NE : en;
                float c0 = 0.f, c1 = 0.f, c2 = 0.f, c3 = 0.f,
                      c4 = 0.f, c5 = 0.f, c6 = 0.f, c7 = 0.f;
                int p = st;
                for (; p + 1 < en; p += 2) {
                    unsigned s0 = (unsigned)adj[p], s1 = (unsigned)adj[p + 1];
                    s0 = s0 < NN ? s0 : NN - 1;
                    s1 = s1 < NN ? s1 : NN - 1;
                    uint4 u0 = *(const uint4*)&h32[(size_t)s0 * 64 + l15 * 4];
                    uint4 u1 = *(const uint4*)&h32[(size_t)s1 * 64 + l15 * 4];
                    a0 += bflo(u0.x); a1 += bfhi(u0.x);
                    a2 += bflo(u0.y); a3 += bfhi(u0.y);
                    a4 += bflo(u0.z); a5 += bfhi(u0.z);
                    a6 += bflo(u0.w); a7 += bfhi(u0.w);
                    c0 += bflo(u1.x); c1 += bfhi(u1.x);
                    c2 += bflo(u1.y); c3 += bfhi(u1.y);
                    c4 += bflo(u1.z); c5 += bfhi(u1.z);
                    c6 += bflo(u1.w); c7 += bfhi(u1.w);
                }
                if (p < en) {
                    unsigned s0 = (unsigned)adj[p];
                    s0 = s0 < NN ? s0 : NN - 1;
                    uint4 u0 = *(const uint4*)&h32[(size_t)s0 * 64 + l15 * 4];
                    a0 += bflo(u0.x); a1 += bfhi(u0.x);
                    a2 += bflo(u0.y); a3 += bfhi(u0.y);
                    a4 += bflo(u0.z); a5 += bfhi(u0.z);
                    a6 += bflo(u0.w); a7 += bfhi(u0.w);
                }
                int d = en - st;
                float sc = 1.0f / (float)(d > 1 ? d : 1);
                a0 = (a0 + c0) * sc; a1 = (a1 + c1) * sc;
                a2 = (a2 + c2) * sc; a3 = (a3 + c3) * sc;
                a4 = (a4 + c4) * sc; a5 = (a5 + c5) * sc;
                a6 = (a6 + c6) * sc; a7 = (a7 + c7) * sc;
            }
            uint4 w;
            w.x = pack2(a0, a1); w.y = pack2(a2, a3);
            w.z = pack2(a4, a5); w.w = pack2(a6, a7);
            *(uint4*)&WB32[row * PADB2 + l15 * 4] = w;
        }
        // no barrier: wave reads its own tile (lgkmcnt orders LDS RAW)
        const unsigned short* WB = wrel + r * 16384;
#pragma unroll
        for (int kk = 0; kk < 4; kk++) {
            short8 af = *(const short8*)&WB16[l15 * PADB + kk * 32 + quad * 8];
#pragma unroll
            for (int ft = 0; ft < 8; ft++) {
                short8 bf = *(const short8*)&WB[((kk * 8 + ft) * 64 + lane) * 8];
                acc[ft] = __builtin_amdgcn_mfma_f32_16x16x32_bf16(af, bf, acc[ft], 0, 0, 0);
            }
        }
    }

    // root transform: wave stages its own 16 h rows, then MFMA with wroot
#pragma unroll
    for (int b = 0; b < 4; b++) {
        int row = b * 4 + quad;
        int g = w0 + row;
        uint4 v = make_uint4(0u, 0u, 0u, 0u);
        if (g < NN) v = *(const uint4*)&h32[(size_t)g * 64 + l15 * 4];
        *(uint4*)&WB32[row * PADB2 + l15 * 4] = v;
    }
#pragma unroll
    for (int kk = 0; kk < 4; kk++) {
        short8 af = *(const short8*)&WB16[l15 * PADB + kk * 32 + quad * 8];
#pragma unroll
        for (int ft = 0; ft < 8; ft++) {
            short8 bf = *(const short8*)&wroot[((kk * 8 + ft) * 64 + lane) * 8];
            acc[ft] = __builtin_amdgcn_mfma_f32_16x16x32_bf16(af, bf, acc[ft], 0, 0, 0);
        }
    }

    // epilogue (wave-private): acc (C layout: row=quad*4+rg, col=ft*16+l15) -> fp32 LDS
#pragma unroll
    for (int ft = 0; ft < 8; ft++)
#pragma unroll
        for (int rg = 0; rg < 4; rg++)
            WF[(quad * 4 + rg) * PADF + ft * 16 + l15] = acc[ft][rg];

    float2 bia = *(const float2*)&bias[2 * lane];
    float2 gam = *(const float2*)&gamma[2 * lane];
    float2 bet = *(const float2*)&beta[2 * lane];

    for (int i = 0; i < 16; i++) {
        int g = w0 + i;
        if (g >= NN) continue;                       // wave-uniform
        float v0 = WF[i * PADF + 2 * lane] + bia.x;
        float v1 = WF[i * PADF + 2 * lane + 1] + bia.y;
        float s = v0 + v1;
#pragma unroll
        for (int off = 32; off > 0; off >>= 1) s += __shfl_xor(s, off, 64);
        float mu = s * (1.0f / ND);
        float e0 = v0 - mu, e1 = v1 - mu;
        float vs = e0 * e0 + e1 * e1;
#pragma unroll
        for (int off = 32; off > 0; off >>= 1) vs += __shfl_xor(vs, off, 64);
        float rr = rsqrtf(vs * (1.0f / ND) + LN_EPS);
        float o0 = fmaxf(e0 * rr * gam.x + bet.x, 0.0f);
        float o1 = fmaxf(e1 * rr * gam.y + bet.y, 0.0f);
        if (add_res) {
            unsigned u = h32[(size_t)g * 64 + lane];
            o0 += bflo(u);
            o1 += bfhi(u);
        }
        if (last) {
            *(float2*)&out_f[(size_t)g * ND + 2 * lane] = make_float2(o0, o1);
        } else {
            out_h[(size_t)g * 64 + lane] = pack2(o0, o1);
        }
    }
}

extern "C" void kernel_launch(void* const* d_in, const int* in_sizes, int n_in,
                              void* d_out, int out_size, void* d_ws, size_t ws_size,
                              hipStream_t stream) {
    const int*   x      = (const int*)d_in[0];
    const int*   ei     = (const int*)d_in[1];
    const int*   et     = (const int*)d_in[2];
    const float* emb    = (const float*)d_in[3];
    const float* w_rel  = (const float*)d_in[4];
    const float* w_root = (const float*)d_in[5];
    const float* bias   = (const float*)d_in[6];
    const float* gamma  = (const float*)d_in[7];
    const float* beta   = (const float*)d_in[8];
    float* out = (float*)d_out;

    char* ws = (char*)d_ws;
    unsigned* h_a      = (unsigned*)(ws);                    // 12.8 MB (bf16x2, row-major)
    unsigned* h_b      = (unsigned*)(ws + 12800000);         // 12.8 MB
    int*      cnt      = (int*)     (ws + 25600000);         // 1.6 MB
    int*      rowstart = (int*)     (ws + 28800000);         // 1.6 MB + 4
    int*      bsum     = (int*)     (ws + 30400064);
    int*      boff     = (int*)     (ws + 30402048);
    int*      adj      = (int*)     (ws + 30404096);         // 6.4 MB
    unsigned short* wb = (unsigned short*)(ws + 36804096);   // 884736 B

    const int* src = ei;
    const int* dst = ei + NE;

    k_prep0<<<(PREP_TOT + 255) / 256, 256, 0, stream>>>(x, emb, w_rel, w_root,
                                                        cnt, h_a, wb);
    k_count<<<(NE / 4 + 255) / 256, 256, 0, stream>>>(dst, et, cnt);
    k_scan1<<<NB, 256, 0, stream>>>(cnt, rowstart, bsum);
    k_scan2<<<1, 256, 0, stream>>>(bsum, boff);
    k_scan3<<<(RN + 255) / 256, 256, 0, stream>>>(rowstart, boff);
    k_fill<<<(NE / 4 + 255) / 256, 256, 0, stream>>>(src, dst, et, rowstart, cnt, adj);

    unsigned* h_cur = h_a;
    unsigned* h_nxt = h_b;
    for (int l = 0; l < NL; l++) {
        k_layer<<<(NN + 63) / 64, 256, 0, stream>>>(
            h_cur, adj, rowstart,
            wb + (size_t)l * 8 * 16384, wb + (size_t)(24 + l) * 16384,
            bias + l * ND, gamma + l * ND, beta + l * ND,
            out, h_nxt, l > 0, l == NL - 1);
        unsigned* t = h_cur; h_cur = h_nxt; h_nxt = t;
    }
}

// Round 13
// 734.145 us; speedup vs baseline: 1.5493x; 1.5493x over previous
//
#include <hip/hip_runtime.h>

#define NN 50000
#define NE 1600000
#define NR 8
#define ND 128
#define NL 3
#define RN (NR * NN)
#define SCAN_BLK 1024
#define NB ((RN + SCAN_BLK - 1) / SCAN_BLK)  // 391
#define LN_EPS 1e-5f
#define PADB 136   // bf16 elems per wave-tile row (272 B row stride)
#define PADB2 68   // dwords per wave-tile row
#define PADF 132   // f32 elems per epilogue scratch row (8448 B per wave region)

// fused prep kernel region sizes
#define PREP_G (NN * 64)        // gather dwords
#define PREP_W (27 * 16384)     // wprep elems
#define PREP_TOT (RN + PREP_G + PREP_W)

typedef __attribute__((ext_vector_type(8))) short short8;
typedef __attribute__((ext_vector_type(4))) float float4v;

__device__ __forceinline__ float bflo(unsigned u) { return __uint_as_float(u << 16); }
__device__ __forceinline__ float bfhi(unsigned u) { return __uint_as_float(u & 0xFFFF0000u); }
__device__ __forceinline__ unsigned f2bf(float f) {
    unsigned u = __float_as_uint(f);
    return (u + 0x7FFFu + ((u >> 16) & 1u)) >> 16;   // RNE
}
__device__ __forceinline__ unsigned pack2(float lo, float hi) {
    return f2bf(lo) | (f2bf(hi) << 16);
}

// fused: cnt zero | h gather (row-major bf16x2) | weight prep (B-frag layout)
__global__ __launch_bounds__(256) void k_prep0(const int* __restrict__ x,
                                               const float* __restrict__ emb,
                                               const float* __restrict__ w_rel,
                                               const float* __restrict__ w_root,
                                               int* __restrict__ cnt,
                                               unsigned* __restrict__ h,
                                               unsigned short* __restrict__ wb) {
    int i = blockIdx.x * 256 + threadIdx.x;
    if (i < RN) {
        cnt[i] = 0;
        return;
    }
    i -= RN;
    if (i < PREP_G) {
        int n = i >> 6, dw = i & 63;
        float2 v = *(const float2*)&emb[(size_t)x[n] * ND + 2 * dw];
        h[i] = pack2(v.x, v.y);
        return;
    }
    i -= PREP_G;
    if (i >= PREP_W) return;
    int m = i >> 14;
    int idx = i & 16383;
    int j = idx & 7;
    int lane = (idx >> 3) & 63;
    int ft = (idx >> 9) & 7;
    int kk = idx >> 12;
    int row = kk * 32 + (lane >> 4) * 8 + j;
    int col = ft * 16 + (lane & 15);
    const float* W = (m < 24) ? (w_rel + (size_t)m * 16384)
                              : (w_root + (size_t)(m - 24) * 16384);
    wb[i] = (unsigned short)f2bf(W[row * ND + col]);
}

__global__ __launch_bounds__(256) void k_count(const int* __restrict__ dst,
                                               const int* __restrict__ et,
                                               int* __restrict__ cnt) {
    int i = blockIdx.x * 256 + threadIdx.x;
    if (i >= NE / 4) return;
    int4 d4 = ((const int4*)dst)[i];
    int4 t4 = ((const int4*)et)[i];
    atomicAdd(&cnt[t4.x * NN + d4.x], 1);
    atomicAdd(&cnt[t4.y * NN + d4.y], 1);
    atomicAdd(&cnt[t4.z * NN + d4.z], 1);
    atomicAdd(&cnt[t4.w * NN + d4.w], 1);
}

// scan over cnt -> rowstart (exclusive)
__global__ __launch_bounds__(256) void k_scan1(const int* __restrict__ cnt,
                                               int* __restrict__ rowstart,
                                               int* __restrict__ bsum) {
    __shared__ int tmp[256];
    int t = threadIdx.x;
    int base = blockIdx.x * SCAN_BLK + t * 4;
    int v[4];
#pragma unroll
    for (int i = 0; i < 4; i++) v[i] = (base + i < RN) ? cnt[base + i] : 0;
    int local = v[0] + v[1] + v[2] + v[3];
    tmp[t] = local;
    __syncthreads();
    for (int off = 1; off < 256; off <<= 1) {
        int x = (t >= off) ? tmp[t - off] : 0;
        __syncthreads();
        tmp[t] += x;
        __syncthreads();
    }
    int run = tmp[t] - local;
    if (t == 255) bsum[blockIdx.x] = tmp[t];
#pragma unroll
    for (int i = 0; i < 4; i++) {
        if (base + i < RN) rowstart[base + i] = run;
        run += v[i];
    }
}

__global__ __launch_bounds__(256) void k_scan2(const int* __restrict__ bsum,
                                               int* __restrict__ boff) {
    __shared__ int tmp[256];
    int t = threadIdx.x;
    int v0 = (2 * t < NB) ? bsum[2 * t] : 0;
    int v1 = (2 * t + 1 < NB) ? bsum[2 * t + 1] : 0;
    int local = v0 + v1;
    tmp[t] = local;
    __syncthreads();
    for (int off = 1; off < 256; off <<= 1) {
        int x = (t >= off) ? tmp[t - off] : 0;
        __syncthreads();
        tmp[t] += x;
        __syncthreads();
    }
    int excl = tmp[t] - local;
    if (2 * t < NB) boff[2 * t] = excl;
    if (2 * t + 1 < NB) boff[2 * t + 1] = excl + v0;
}

__global__ __launch_bounds__(256) void k_scan3(int* __restrict__ rowstart,
                                               const int* __restrict__ boff) {
    int i = blockIdx.x * 256 + threadIdx.x;
    if (i < RN) rowstart[i] += boff[i >> 10];
    if (i == 0) rowstart[RN] = NE;
}

__global__ __launch_bounds__(256) void k_fill(const int* __restrict__ src,
                                              const int* __restrict__ dst,
                                              const int* __restrict__ et,
                                              const int* __restrict__ rowstart,
                                              int* __restrict__ cnt,
                                              int* __restrict__ adj) {
    int i = blockIdx.x * 256 + threadIdx.x;
    if (i >= NE / 4) return;
    int4 s4 = ((const int4*)src)[i];
    int4 d4 = ((const int4*)dst)[i];
    int4 t4 = ((const int4*)et)[i];
    int seg, c;
    seg = t4.x * NN + d4.x; c = atomicSub(&cnt[seg], 1); adj[rowstart[seg] + c - 1] = s4.x;
    seg = t4.y * NN + d4.y; c = atomicSub(&cnt[seg], 1); adj[rowstart[seg] + c - 1] = s4.y;
    seg = t4.z * NN + d4.z; c = atomicSub(&cnt[seg], 1); adj[rowstart[seg] + c - 1] = s4.z;
    seg = t4.w * NN + d4.w; c = atomicSub(&cnt[seg], 1); adj[rowstart[seg] + c - 1] = s4.w;
}

// Fused RGCN layer, WAVE-AUTONOMOUS (exact R10 structure + 4-deep edge ILP):
// block = 64 nodes, 4 waves; each wave owns a 16-row m-tile + private LDS
// region; zero __syncthreads. Mean scale computed from en-st (no inv load).
__global__ __launch_bounds__(256) void k_layer(const unsigned* __restrict__ h32,
                                               const int* __restrict__ adj,
                                               const int* __restrict__ rowstart,
                                               const unsigned short* __restrict__ wrel,
                                               const unsigned short* __restrict__ wroot,
                                               const float* __restrict__ bias,
                                               const float* __restrict__ gamma,
                                               const float* __restrict__ beta,
                                               float* __restrict__ out_f,
                                               unsigned* __restrict__ out_h,
                                               int add_res, int last) {
    __shared__ float SLF[4][16 * PADF];              // per-wave 8448 B regions

    int tid = threadIdx.x;
    int wave = tid >> 6, lane = tid & 63;
    int quad = lane >> 4, l15 = lane & 15;
    int n0 = blockIdx.x * 64;
    int w0 = n0 + wave * 16;                         // wave's first global row

    float* WF = SLF[wave];                           // fp32 [16][PADF] epilogue view
    unsigned short* WB16 = (unsigned short*)WF;      // bf16 [16][PADB] tile view
    unsigned* WB32 = (unsigned*)WF;                  // dword [16][PADB2] tile view

    float4v acc[8];
#pragma unroll
    for (int i = 0; i < 8; i++) acc[i] = (float4v){0.f, 0.f, 0.f, 0.f};

    for (int r = 0; r < NR; r++) {
        // gather+mean: 4 batches of 4 quad-chains (rows 0..15), 4-edge ILP
        for (int b = 0; b < 4; b++) {
            int row = b * 4 + quad;
            int g = w0 + row;
            float a0 = 0.f, a1 = 0.f, a2 = 0.f, a3 = 0.f,
                  a4 = 0.f, a5 = 0.f, a6 = 0.f, a7 = 0.f;
            if (g < NN) {
                int seg = r * NN + g;
                int st = rowstart[seg], en = rowstart[seg + 1];
                st = st < 0 ? 0 : st;
                en = en > NE ? NE : en;
                float c0 = 0.f, c1 = 0.f, c2 = 0.f, c3 = 0.f,
                      c4 = 0.f, c5 = 0.f, c6 = 0.f, c7 = 0.f;
                int p = st;
                for (; p + 3 < en; p += 4) {
                    unsigned s0 = (unsigned)adj[p],     s1 = (unsigned)adj[p + 1];
                    unsigned s2 = (unsigned)adj[p + 2], s3 = (unsigned)adj[p + 3];
                    s0 = s0 < NN ? s0 : NN - 1;
                    s1 = s1 < NN ? s1 : NN - 1;
                    s2 = s2 < NN ? s2 : NN - 1;
                    s3 = s3 < NN ? s3 : NN - 1;
                    uint4 u0 = *(const uint4*)&h32[(size_t)s0 * 64 + l15 * 4];
                    uint4 u1 = *(const uint4*)&h32[(size_t)s1 * 64 + l15 * 4];
                    uint4 u2 = *(const uint4*)&h32[(size_t)s2 * 64 + l15 * 4];
                    uint4 u3 = *(const uint4*)&h32[(size_t)s3 * 64 + l15 * 4];
                    a0 += bflo(u0.x); a1 += bfhi(u0.x);
                    a2 += bflo(u0.y); a3 += bfhi(u0.y);
                    a4 += bflo(u0.z); a5 += bfhi(u0.z);
                    a6 += bflo(u0.w); a7 += bfhi(u0.w);
                    c0 += bflo(u1.x); c1 += bfhi(u1.x);
                    c2 += bflo(u1.y); c3 += bfhi(u1.y);
                    c4 += bflo(u1.z); c5 += bfhi(u1.z);
                    c6 += bflo(u1.w); c7 += bfhi(u1.w);
                    a0 += bflo(u2.x); a1 += bfhi(u2.x);
                    a2 += bflo(u2.y); a3 += bfhi(u2.y);
                    a4 += bflo(u2.z); a5 += bfhi(u2.z);
                    a6 += bflo(u2.w); a7 += bfhi(u2.w);
                    c0 += bflo(u3.x); c1 += bfhi(u3.x);
                    c2 += bflo(u3.y); c3 += bfhi(u3.y);
                    c4 += bflo(u3.z); c5 += bfhi(u3.z);
                    c6 += bflo(u3.w); c7 += bfhi(u3.w);
                }
                for (; p + 1 < en; p += 2) {
                    unsigned s0 = (unsigned)adj[p], s1 = (unsigned)adj[p + 1];
                    s0 = s0 < NN ? s0 : NN - 1;
                    s1 = s1 < NN ? s1 : NN - 1;
                    uint4 u0 = *(const uint4*)&h32[(size_t)s0 * 64 + l15 * 4];
                    uint4 u1 = *(const uint4*)&h32[(size_t)s1 * 64 + l15 * 4];
                    a0 += bflo(u0.x); a1 += bfhi(u0.x);
                    a2 += bflo(u0.y); a3 += bfhi(u0.y);
                    a4 += bflo(u0.z); a5 += bfhi(u0.z);
                    a6 += bflo(u0.w); a7 += bfhi(u0.w);
                    c0 += bflo(u1.x); c1 += bfhi(u1.x);
                    c2 += bflo(u1.y); c3 += bfhi(u1.y);
                    c4 += bflo(u1.z); c5 += bfhi(u1.z);
                    c6 += bflo(u1.w); c7 += bfhi(u1.w);
                }
                if (p < en) {
                    unsigned s0 = (unsigned)adj[p];
                    s0 = s0 < NN ? s0 : NN - 1;
                    uint4 u0 = *(const uint4*)&h32[(size_t)s0 * 64 + l15 * 4];
                    a0 += bflo(u0.x); a1 += bfhi(u0.x);
                    a2 += bflo(u0.y); a3 += bfhi(u0.y);
                    a4 += bflo(u0.z); a5 += bfhi(u0.z);
                    a6 += bflo(u0.w); a7 += bfhi(u0.w);
                }
                int d = en - st;
                float sc = 1.0f / (float)(d > 1 ? d : 1);
                a0 = (a0 + c0) * sc; a1 = (a1 + c1) * sc;
                a2 = (a2 + c2) * sc; a3 = (a3 + c3) * sc;
                a4 = (a4 + c4) * sc; a5 = (a5 + c5) * sc;
                a6 = (a6 + c6) * sc; a7 = (a7 + c7) * sc;
            }
            uint4 w;
            w.x = pack2(a0, a1); w.y = pack2(a2, a3);
            w.z = pack2(a4, a5); w.w = pack2(a6, a7);
            *(uint4*)&WB32[row * PADB2 + l15 * 4] = w;
        }
        // no barrier: wave reads its own tile (lgkmcnt orders LDS RAW)
        const unsigned short* WB = wrel + r * 16384;
#pragma unroll
        for (int kk = 0; kk < 4; kk++) {
            short8 af = *(const short8*)&WB16[l15 * PADB + kk * 32 + quad * 8];
#pragma unroll
            for (int ft = 0; ft < 8; ft++) {
                short8 bf = *(const short8*)&WB[((kk * 8 + ft) * 64 + lane) * 8];
                acc[ft] = __builtin_amdgcn_mfma_f32_16x16x32_bf16(af, bf, acc[ft], 0, 0, 0);
            }
        }
    }

    // root transform: wave stages its own 16 h rows, then MFMA with wroot
#pragma unroll
    for (int b = 0; b < 4; b++) {
        int row = b * 4 + quad;
        int g = w0 + row;
        uint4 v = make_uint4(0u, 0u, 0u, 0u);
        if (g < NN) v = *(const uint4*)&h32[(size_t)g * 64 + l15 * 4];
        *(uint4*)&WB32[row * PADB2 + l15 * 4] = v;
    }
#pragma unroll
    for (int kk = 0; kk < 4; kk++) {
        short8 af = *(const short8*)&WB16[l15 * PADB + kk * 32 + quad * 8];
#pragma unroll
        for (int ft = 0; ft < 8; ft++) {
            short8 bf = *(const short8*)&wroot[((kk * 8 + ft) * 64 + lane) * 8];
            acc[ft] = __builtin_amdgcn_mfma_f32_16x16x32_bf16(af, bf, acc[ft], 0, 0, 0);
        }
    }

    // epilogue (wave-private): acc (C layout: row=quad*4+rg, col=ft*16+l15) -> fp32 LDS
#pragma unroll
    for (int ft = 0; ft < 8; ft++)
#pragma unroll
        for (int rg = 0; rg < 4; rg++)
            WF[(quad * 4 + rg) * PADF + ft * 16 + l15] = acc[ft][rg];

    float2 bia = *(const float2*)&bias[2 * lane];
    float2 gam = *(const float2*)&gamma[2 * lane];
    float2 bet = *(const float2*)&beta[2 * lane];

    for (int i = 0; i < 16; i++) {
        int g = w0 + i;
        if (g >= NN) continue;                       // wave-uniform
        float v0 = WF[i * PADF + 2 * lane] + bia.x;
        float v1 = WF[i * PADF + 2 * lane + 1] + bia.y;
        float s = v0 + v1;
#pragma unroll
        for (int off = 32; off > 0; off >>= 1) s += __shfl_xor(s, off, 64);
        float mu = s * (1.0f / ND);
        float e0 = v0 - mu, e1 = v1 - mu;
        float vs = e0 * e0 + e1 * e1;
#pragma unroll
        for (int off = 32; off > 0; off >>= 1) vs += __shfl_xor(vs, off, 64);
        float rr = rsqrtf(vs * (1.0f / ND) + LN_EPS);
        float o0 = fmaxf(e0 * rr * gam.x + bet.x, 0.0f);
        float o1 = fmaxf(e1 * rr * gam.y + bet.y, 0.0f);
        if (add_res) {
            unsigned u = h32[(size_t)g * 64 + lane];
            o0 += bflo(u);
            o1 += bfhi(u);
        }
        if (last) {
            *(float2*)&out_f[(size_t)g * ND + 2 * lane] = make_float2(o0, o1);
        } else {
            out_h[(size_t)g * 64 + lane] = pack2(o0, o1);
        }
    }
}

extern "C" void kernel_launch(void* const* d_in, const int* in_sizes, int n_in,
                              void* d_out, int out_size, void* d_ws, size_t ws_size,
                              hipStream_t stream) {
    const int*   x      = (const int*)d_in[0];
    const int*   ei     = (const int*)d_in[1];
    const int*   et     = (const int*)d_in[2];
    const float* emb    = (const float*)d_in[3];
    const float* w_rel  = (const float*)d_in[4];
    const float* w_root = (const float*)d_in[5];
    const float* bias   = (const float*)d_in[6];
    const float* gamma  = (const float*)d_in[7];
    const float* beta   = (const float*)d_in[8];
    float* out = (float*)d_out;

    char* ws = (char*)d_ws;
    unsigned* h_a      = (unsigned*)(ws);                    // 12.8 MB (bf16x2, row-major)
    unsigned* h_b      = (unsigned*)(ws + 12800000);         // 12.8 MB
    int*      cnt      = (int*)     (ws + 25600000);         // 1.6 MB
    int*      rowstart = (int*)     (ws + 28800000);         // 1.6 MB + 4
    int*      bsum     = (int*)     (ws + 30400064);
    int*      boff     = (int*)     (ws + 30402048);
    int*      adj      = (int*)     (ws + 30404096);         // 6.4 MB
    unsigned short* wb = (unsigned short*)(ws + 36804096);   // 884736 B

    const int* src = ei;
    const int* dst = ei + NE;

    k_prep0<<<(PREP_TOT + 255) / 256, 256, 0, stream>>>(x, emb, w_rel, w_root,
                                                        cnt, h_a, wb);
    k_count<<<(NE / 4 + 255) / 256, 256, 0, stream>>>(dst, et, cnt);
    k_scan1<<<NB, 256, 0, stream>>>(cnt, rowstart, bsum);
    k_scan2<<<1, 256, 0, stream>>>(bsum, boff);
    k_scan3<<<(RN + 255) / 256, 256, 0, stream>>>(rowstart, boff);
    k_fill<<<(NE / 4 + 255) / 256, 256, 0, stream>>>(src, dst, et, rowstart, cnt, adj);

    unsigned* h_cur = h_a;
    unsigned* h_nxt = h_b;
    for (int l = 0; l < NL; l++) {
        k_layer<<<(NN + 63) / 64, 256, 0, stream>>>(
            h_cur, adj, rowstart,
            wb + (size_t)l * 8 * 16384, wb + (size_t)(24 + l) * 16384,
            bias + l * ND, gamma + l * ND, beta + l * ND,
            out, h_nxt, l > 0, l == NL - 1);
        unsigned* t = h_cur; h_cur = h_nxt; h_nxt = t;
    }
}

// Round 14
// 632.232 us; speedup vs baseline: 1.7990x; 1.1612x over previous
//
#include <hip/hip_runtime.h>

#define NN 50000
#define NE 1600000
#define NR 8
#define ND 128
#define NL 3
#define RN (NR * NN)
#define SCAN_BLK 1024
#define NB ((RN + SCAN_BLK - 1) / SCAN_BLK)  // 391
#define LN_EPS 1e-5f
#define PADF 132   // f32 elems per epilogue scratch row (8448 B per wave region)

// fused prep kernel region sizes
#define PREP_G (NN * 64)        // gather dwords
#define PREP_W (27 * 16384)     // wprep elems
#define PREP_TOT (RN + PREP_G + PREP_W)

typedef __attribute__((ext_vector_type(8))) short short8;
typedef __attribute__((ext_vector_type(4))) float float4v;

__device__ __forceinline__ float bflo(unsigned u) { return __uint_as_float(u << 16); }
__device__ __forceinline__ float bfhi(unsigned u) { return __uint_as_float(u & 0xFFFF0000u); }
__device__ __forceinline__ unsigned f2bf(float f) {
    unsigned u = __float_as_uint(f);
    return (u + 0x7FFFu + ((u >> 16) & 1u)) >> 16;   // RNE
}
__device__ __forceinline__ unsigned pack2(float lo, float hi) {
    return f2bf(lo) | (f2bf(hi) << 16);
}

// fused: cnt zero | h gather (row-major bf16x2) | weight prep (B-frag layout)
__global__ __launch_bounds__(256) void k_prep0(const int* __restrict__ x,
                                               const float* __restrict__ emb,
                                               const float* __restrict__ w_rel,
                                               const float* __restrict__ w_root,
                                               int* __restrict__ cnt,
                                               unsigned* __restrict__ h,
                                               unsigned short* __restrict__ wb) {
    int i = blockIdx.x * 256 + threadIdx.x;
    if (i < RN) {
        cnt[i] = 0;
        return;
    }
    i -= RN;
    if (i < PREP_G) {
        int n = i >> 6, dw = i & 63;
        float2 v = *(const float2*)&emb[(size_t)x[n] * ND + 2 * dw];
        h[i] = pack2(v.x, v.y);
        return;
    }
    i -= PREP_G;
    if (i >= PREP_W) return;
    int m = i >> 14;
    int idx = i & 16383;
    int j = idx & 7;
    int lane = (idx >> 3) & 63;
    int ft = (idx >> 9) & 7;
    int kk = idx >> 12;
    int row = kk * 32 + (lane >> 4) * 8 + j;
    int col = ft * 16 + (lane & 15);
    const float* W = (m < 24) ? (w_rel + (size_t)m * 16384)
                              : (w_root + (size_t)(m - 24) * 16384);
    wb[i] = (unsigned short)f2bf(W[row * ND + col]);
}

__global__ __launch_bounds__(256) void k_count(const int* __restrict__ dst,
                                               const int* __restrict__ et,
                                               int* __restrict__ cnt) {
    int i = blockIdx.x * 256 + threadIdx.x;
    if (i >= NE / 4) return;
    int4 d4 = ((const int4*)dst)[i];
    int4 t4 = ((const int4*)et)[i];
    atomicAdd(&cnt[t4.x * NN + d4.x], 1);
    atomicAdd(&cnt[t4.y * NN + d4.y], 1);
    atomicAdd(&cnt[t4.z * NN + d4.z], 1);
    atomicAdd(&cnt[t4.w * NN + d4.w], 1);
}

// scan over cnt -> rowstart (exclusive)
__global__ __launch_bounds__(256) void k_scan1(const int* __restrict__ cnt,
                                               int* __restrict__ rowstart,
                                               int* __restrict__ bsum) {
    __shared__ int tmp[256];
    int t = threadIdx.x;
    int base = blockIdx.x * SCAN_BLK + t * 4;
    int v[4];
#pragma unroll
    for (int i = 0; i < 4; i++) v[i] = (base + i < RN) ? cnt[base + i] : 0;
    int local = v[0] + v[1] + v[2] + v[3];
    tmp[t] = local;
    __syncthreads();
    for (int off = 1; off < 256; off <<= 1) {
        int x = (t >= off) ? tmp[t - off] : 0;
        __syncthreads();
        tmp[t] += x;
        __syncthreads();
    }
    int run = tmp[t] - local;
    if (t == 255) bsum[blockIdx.x] = tmp[t];
#pragma unroll
    for (int i = 0; i < 4; i++) {
        if (base + i < RN) rowstart[base + i] = run;
        run += v[i];
    }
}

__global__ __launch_bounds__(256) void k_scan2(const int* __restrict__ bsum,
                                               int* __restrict__ boff) {
    __shared__ int tmp[256];
    int t = threadIdx.x;
    int v0 = (2 * t < NB) ? bsum[2 * t] : 0;
    int v1 = (2 * t + 1 < NB) ? bsum[2 * t + 1] : 0;
    int local = v0 + v1;
    tmp[t] = local;
    __syncthreads();
    for (int off = 1; off < 256; off <<= 1) {
        int x = (t >= off) ? tmp[t - off] : 0;
        __syncthreads();
        tmp[t] += x;
        __syncthreads();
    }
    int excl = tmp[t] - local;
    if (2 * t < NB) boff[2 * t] = excl;
    if (2 * t + 1 < NB) boff[2 * t + 1] = excl + v0;
}

__global__ __launch_bounds__(256) void k_scan3(int* __restrict__ rowstart,
                                               const int* __restrict__ boff) {
    int i = blockIdx.x * 256 + threadIdx.x;
    if (i < RN) rowstart[i] += boff[i >> 10];
    if (i == 0) rowstart[RN] = NE;
}

__global__ __launch_bounds__(256) void k_fill(const int* __restrict__ src,
                                              const int* __restrict__ dst,
                                              const int* __restrict__ et,
                                              const int* __restrict__ rowstart,
                                              int* __restrict__ cnt,
                                              int* __restrict__ adj) {
    int i = blockIdx.x * 256 + threadIdx.x;
    if (i >= NE / 4) return;
    int4 s4 = ((const int4*)src)[i];
    int4 d4 = ((const int4*)dst)[i];
    int4 t4 = ((const int4*)et)[i];
    int seg, c;
    seg = t4.x * NN + d4.x; c = atomicSub(&cnt[seg], 1); adj[rowstart[seg] + c - 1] = s4.x;
    seg = t4.y * NN + d4.y; c = atomicSub(&cnt[seg], 1); adj[rowstart[seg] + c - 1] = s4.y;
    seg = t4.z * NN + d4.z; c = atomicSub(&cnt[seg], 1); adj[rowstart[seg] + c - 1] = s4.z;
    seg = t4.w * NN + d4.w; c = atomicSub(&cnt[seg], 1); adj[rowstart[seg] + c - 1] = s4.w;
}

// Pure aggregation: one 16-lane quad per (relation,dst) segment. No LDS, no
// barriers, minimal VGPR -> max residency (32 waves/CU). Writes mean rows
// (bf16x2 packed) to S[n][r][*]: dword index n*512 + r*64 + l15*4.
__global__ __launch_bounds__(256) void k_agg(const unsigned* __restrict__ h32,
                                             const int* __restrict__ adj,
                                             const int* __restrict__ rowstart,
                                             unsigned* __restrict__ S) {
    int q = (blockIdx.x * 256 + threadIdx.x) >> 4;   // segment id (grid exact)
    int l15 = threadIdx.x & 15;
    int r = q / NN;
    int n = q - r * NN;
    int st = rowstart[q], en = rowstart[q + 1];
    st = st < 0 ? 0 : st;
    en = en > NE ? NE : en;
    float a0 = 0.f, a1 = 0.f, a2 = 0.f, a3 = 0.f,
          a4 = 0.f, a5 = 0.f, a6 = 0.f, a7 = 0.f;
    float c0 = 0.f, c1 = 0.f, c2 = 0.f, c3 = 0.f,
          c4 = 0.f, c5 = 0.f, c6 = 0.f, c7 = 0.f;
    int p = st;
    for (; p + 3 < en; p += 4) {
        unsigned s0 = (unsigned)adj[p],     s1 = (unsigned)adj[p + 1];
        unsigned s2 = (unsigned)adj[p + 2], s3 = (unsigned)adj[p + 3];
        s0 = s0 < NN ? s0 : NN - 1;
        s1 = s1 < NN ? s1 : NN - 1;
        s2 = s2 < NN ? s2 : NN - 1;
        s3 = s3 < NN ? s3 : NN - 1;
        uint4 u0 = *(const uint4*)&h32[(size_t)s0 * 64 + l15 * 4];
        uint4 u1 = *(const uint4*)&h32[(size_t)s1 * 64 + l15 * 4];
        uint4 u2 = *(const uint4*)&h32[(size_t)s2 * 64 + l15 * 4];
        uint4 u3 = *(const uint4*)&h32[(size_t)s3 * 64 + l15 * 4];
        a0 += bflo(u0.x); a1 += bfhi(u0.x);
        a2 += bflo(u0.y); a3 += bfhi(u0.y);
        a4 += bflo(u0.z); a5 += bfhi(u0.z);
        a6 += bflo(u0.w); a7 += bfhi(u0.w);
        c0 += bflo(u1.x); c1 += bfhi(u1.x);
        c2 += bflo(u1.y); c3 += bfhi(u1.y);
        c4 += bflo(u1.z); c5 += bfhi(u1.z);
        c6 += bflo(u1.w); c7 += bfhi(u1.w);
        a0 += bflo(u2.x); a1 += bfhi(u2.x);
        a2 += bflo(u2.y); a3 += bfhi(u2.y);
        a4 += bflo(u2.z); a5 += bfhi(u2.z);
        a6 += bflo(u2.w); a7 += bfhi(u2.w);
        c0 += bflo(u3.x); c1 += bfhi(u3.x);
        c2 += bflo(u3.y); c3 += bfhi(u3.y);
        c4 += bflo(u3.z); c5 += bfhi(u3.z);
        c6 += bflo(u3.w); c7 += bfhi(u3.w);
    }
    for (; p + 1 < en; p += 2) {
        unsigned s0 = (unsigned)adj[p], s1 = (unsigned)adj[p + 1];
        s0 = s0 < NN ? s0 : NN - 1;
        s1 = s1 < NN ? s1 : NN - 1;
        uint4 u0 = *(const uint4*)&h32[(size_t)s0 * 64 + l15 * 4];
        uint4 u1 = *(const uint4*)&h32[(size_t)s1 * 64 + l15 * 4];
        a0 += bflo(u0.x); a1 += bfhi(u0.x);
        a2 += bflo(u0.y); a3 += bfhi(u0.y);
        a4 += bflo(u0.z); a5 += bfhi(u0.z);
        a6 += bflo(u0.w); a7 += bfhi(u0.w);
        c0 += bflo(u1.x); c1 += bfhi(u1.x);
        c2 += bflo(u1.y); c3 += bfhi(u1.y);
        c4 += bflo(u1.z); c5 += bfhi(u1.z);
        c6 += bflo(u1.w); c7 += bfhi(u1.w);
    }
    if (p < en) {
        unsigned s0 = (unsigned)adj[p];
        s0 = s0 < NN ? s0 : NN - 1;
        uint4 u0 = *(const uint4*)&h32[(size_t)s0 * 64 + l15 * 4];
        a0 += bflo(u0.x); a1 += bfhi(u0.x);
        a2 += bflo(u0.y); a3 += bfhi(u0.y);
        a4 += bflo(u0.z); a5 += bfhi(u0.z);
        a6 += bflo(u0.w); a7 += bfhi(u0.w);
    }
    int d = en - st;
    float sc = 1.0f / (float)(d > 1 ? d : 1);
    a0 = (a0 + c0) * sc; a1 = (a1 + c1) * sc;
    a2 = (a2 + c2) * sc; a3 = (a3 + c3) * sc;
    a4 = (a4 + c4) * sc; a5 = (a5 + c5) * sc;
    a6 = (a6 + c6) * sc; a7 = (a7 + c7) * sc;
    uint4 w;
    w.x = pack2(a0, a1); w.y = pack2(a2, a3);
    w.z = pack2(a4, a5); w.w = pack2(a6, a7);
    *(uint4*)&S[(size_t)n * 512 + r * 64 + l15 * 4] = w;
}

// GEMM + LN: out = LN([S | h] @ [W_cat; W_root]) (+ residual), h updated
// in-place. Wave-autonomous: each wave owns a 16-row m-tile; A-fragments read
// straight from global (no reuse -> no LDS staging); LDS only for LN scratch.
__global__ __launch_bounds__(256) void k_gemm(const unsigned* __restrict__ S,
                                              unsigned* __restrict__ h32,
                                              const unsigned short* __restrict__ wrel,
                                              const unsigned short* __restrict__ wroot,
                                              const float* __restrict__ bias,
                                              const float* __restrict__ gamma,
                                              const float* __restrict__ beta,
                                              float* __restrict__ out_f,
                                              int add_res, int last) {
    __shared__ float SLF[4][16 * PADF];

    int tid = threadIdx.x;
    int wave = tid >> 6, lane = tid & 63;
    int quad = lane >> 4, l15 = lane & 15;
    int w0 = blockIdx.x * 64 + wave * 16;
    int gi = w0 + l15; gi = gi < NN ? gi : NN - 1;   // clamped A-row for loads
    float* WF = SLF[wave];

    float4v acc[8];
#pragma unroll
    for (int i = 0; i < 8; i++) acc[i] = (float4v){0.f, 0.f, 0.f, 0.f};

    const unsigned* Sr = S + (size_t)gi * 512;
    for (int r = 0; r < NR; r++) {
        const unsigned short* WB = wrel + r * 16384;
#pragma unroll
        for (int kk = 0; kk < 4; kk++) {
            short8 af = *(const short8*)&Sr[r * 64 + kk * 16 + quad * 4];
#pragma unroll
            for (int ft = 0; ft < 8; ft++) {
                short8 bf = *(const short8*)&WB[((kk * 8 + ft) * 64 + lane) * 8];
                acc[ft] = __builtin_amdgcn_mfma_f32_16x16x32_bf16(af, bf, acc[ft], 0, 0, 0);
            }
        }
    }
    // root transform: A from h (row-major bf16x2)
    const unsigned* Hr = h32 + (size_t)gi * 64;
#pragma unroll
    for (int kk = 0; kk < 4; kk++) {
        short8 af = *(const short8*)&Hr[kk * 16 + quad * 4];
#pragma unroll
        for (int ft = 0; ft < 8; ft++) {
            short8 bf = *(const short8*)&wroot[((kk * 8 + ft) * 64 + lane) * 8];
            acc[ft] = __builtin_amdgcn_mfma_f32_16x16x32_bf16(af, bf, acc[ft], 0, 0, 0);
        }
    }

    // epilogue (wave-private): acc (C layout: row=quad*4+rg, col=ft*16+l15) -> fp32 LDS
#pragma unroll
    for (int ft = 0; ft < 8; ft++)
#pragma unroll
        for (int rg = 0; rg < 4; rg++)
            WF[(quad * 4 + rg) * PADF + ft * 16 + l15] = acc[ft][rg];

    float2 bia = *(const float2*)&bias[2 * lane];
    float2 gam = *(const float2*)&gamma[2 * lane];
    float2 bet = *(const float2*)&beta[2 * lane];

    for (int i = 0; i < 16; i++) {
        int g = w0 + i;
        if (g >= NN) continue;                       // wave-uniform
        float v0 = WF[i * PADF + 2 * lane] + bia.x;
        float v1 = WF[i * PADF + 2 * lane + 1] + bia.y;
        float s = v0 + v1;
#pragma unroll
        for (int off = 32; off > 0; off >>= 1) s += __shfl_xor(s, off, 64);
        float mu = s * (1.0f / ND);
        float e0 = v0 - mu, e1 = v1 - mu;
        float vs = e0 * e0 + e1 * e1;
#pragma unroll
        for (int off = 32; off > 0; off >>= 1) vs += __shfl_xor(vs, off, 64);
        float rr = rsqrtf(vs * (1.0f / ND) + LN_EPS);
        float o0 = fmaxf(e0 * rr * gam.x + bet.x, 0.0f);
        float o1 = fmaxf(e1 * rr * gam.y + bet.y, 0.0f);
        if (add_res) {
            unsigned u = h32[(size_t)g * 64 + lane];
            o0 += bflo(u);
            o1 += bfhi(u);
        }
        if (last) {
            *(float2*)&out_f[(size_t)g * ND + 2 * lane] = make_float2(o0, o1);
        } else {
            h32[(size_t)g * 64 + lane] = pack2(o0, o1);   // in-place update
        }
    }
}

extern "C" void kernel_launch(void* const* d_in, const int* in_sizes, int n_in,
                              void* d_out, int out_size, void* d_ws, size_t ws_size,
                              hipStream_t stream) {
    const int*   x      = (const int*)d_in[0];
    const int*   ei     = (const int*)d_in[1];
    const int*   et     = (const int*)d_in[2];
    const float* emb    = (const float*)d_in[3];
    const float* w_rel  = (const float*)d_in[4];
    const float* w_root = (const float*)d_in[5];
    const float* bias   = (const float*)d_in[6];
    const float* gamma  = (const float*)d_in[7];
    const float* beta   = (const float*)d_in[8];
    float* out = (float*)d_out;

    char* ws = (char*)d_ws;
    unsigned* h        = (unsigned*)(ws);                    // 12.8 MB (bf16x2, row-major)
    int*      cnt      = (int*)     (ws + 12800000);         // 1.6 MB
    int*      rowstart = (int*)     (ws + 14400000);         // 1.6 MB + 4
    int*      bsum     = (int*)     (ws + 16000064);
    int*      boff     = (int*)     (ws + 16002048);
    int*      adj      = (int*)     (ws + 16004096);         // 6.4 MB
    unsigned short* wb = (unsigned short*)(ws + 22404096);   // 884736 B
    unsigned* S        = (unsigned*)(ws + 23288832);         // 102.4 MB

    const int* src = ei;
    const int* dst = ei + NE;

    k_prep0<<<(PREP_TOT + 255) / 256, 256, 0, stream>>>(x, emb, w_rel, w_root,
                                                        cnt, h, wb);
    k_count<<<(NE / 4 + 255) / 256, 256, 0, stream>>>(dst, et, cnt);
    k_scan1<<<NB, 256, 0, stream>>>(cnt, rowstart, bsum);
    k_scan2<<<1, 256, 0, stream>>>(bsum, boff);
    k_scan3<<<(RN + 255) / 256, 256, 0, stream>>>(rowstart, boff);
    k_fill<<<(NE / 4 + 255) / 256, 256, 0, stream>>>(src, dst, et, rowstart, cnt, adj);

    for (int l = 0; l < NL; l++) {
        k_agg<<<RN * 16 / 256, 256, 0, stream>>>(h, adj, rowstart, S);
        k_gemm<<<(NN + 63) / 64, 256, 0, stream>>>(
            S, h,
            wb + (size_t)l * 8 * 16384, wb + (size_t)(24 + l) * 16384,
            bias + l * ND, gamma + l * ND, beta + l * ND,
            out, l > 0, l == NL - 1);
    }
}